// Round 2
// baseline (502.584 us; speedup 1.0000x reference)
//
#include <hip/hip_runtime.h>
#include <cstdint>
#include <cstddef>

#define NT 256
#define DFEAT 128
#define SCAN_ELEMS 1024
#define GEMM_ROWS 128    // rows per gemm block (4 waves x 32 rows)
#define BPAD 136         // padded LDS k-stride (ushorts) for W^T tiles

typedef __attribute__((ext_vector_type(8))) short s8v;
typedef __attribute__((ext_vector_type(4))) float f32x4;

__device__ inline ushort f2bf(float f) {           // RNE fp32 -> bf16
  uint32_t u = __float_as_uint(f);
  u += 0x7fffu + ((u >> 16) & 1u);
  return (ushort)(u >> 16);
}
__device__ inline void accw_bf4(uint2 v, float w, float& a0, float& a1, float& a2, float& a3) {
  a0 = fmaf(w, __uint_as_float(v.x << 16), a0);
  a1 = fmaf(w, __uint_as_float(v.x & 0xffff0000u), a1);
  a2 = fmaf(w, __uint_as_float(v.y << 16), a2);
  a3 = fmaf(w, __uint_as_float(v.y & 0xffff0000u), a3);
}

// ---------- zero int array ----------
__global__ void zero_k(int* __restrict__ p, int n) {
  int i = blockIdx.x * NT + threadIdx.x;
  if (i < n) p[i] = 0;
}

// ---------- histogram of dst, both graphs in one dispatch ----------
__global__ void hist2_k(const int* __restrict__ e_dst, int E,
                        const int* __restrict__ c_dst, int EC,
                        int* __restrict__ cnt_c, int* __restrict__ cnt_t) {
  int i = blockIdx.x * NT + threadIdx.x;
  if (i < E) atomicAdd(&cnt_c[e_dst[i]], 1);
  else if (i < E + EC) atomicAdd(&cnt_t[c_dst[i - E]], 1);
}

// ---------- scan pass A ----------
__global__ __launch_bounds__(NT) void scan_partial_k(
    const int* __restrict__ cnt_c, const int* __restrict__ cnt_t, int n,
    int* __restrict__ bsum, int nb_c) {
  int isT = blockIdx.x >= nb_c;
  const int* cnt = isT ? cnt_t : cnt_c;
  int b = isT ? blockIdx.x - nb_c : blockIdx.x;
  int base = b * SCAN_ELEMS + threadIdx.x * 4;

  int s = 0;
  if (base + 3 < n) {
    int4 v = *(const int4*)&cnt[base];
    s = v.x + v.y + v.z + v.w;
  } else {
    for (int j = 0; j < 4; j++) if (base + j < n) s += cnt[base + j];
  }
  for (int off = 32; off > 0; off >>= 1) s += __shfl_down(s, off, 64);
  __shared__ int ws[4];
  int lane = threadIdx.x & 63, w = threadIdx.x >> 6;
  if (lane == 0) ws[w] = s;
  __syncthreads();
  if (threadIdx.x == 0) bsum[blockIdx.x] = ws[0] + ws[1] + ws[2] + ws[3];
}

// ---------- scan pass B ----------
__global__ __launch_bounds__(NT) void scan_offsets_k(
    int* __restrict__ bsum, int nb_c, int nb_t,
    int* __restrict__ rp_c, int* __restrict__ rp_t, int n) {
  int seg_off = (blockIdx.x == 0) ? 0 : nb_c;
  int nb = (blockIdx.x == 0) ? nb_c : nb_t;
  int* rp = (blockIdx.x == 0) ? rp_c : rp_t;

  __shared__ int ls[NT];
  int t = threadIdx.x;
  int v = (t < nb) ? bsum[seg_off + t] : 0;
  ls[t] = v;
  __syncthreads();
  for (int off = 1; off < NT; off <<= 1) {
    int u = (t >= off) ? ls[t - off] : 0;
    __syncthreads();
    ls[t] += u;
    __syncthreads();
  }
  if (t < nb) bsum[seg_off + t] = ls[t] - v;
  if (t == nb - 1) rp[n] = ls[t];
}

// ---------- scan pass C: rowptr out; cursor array seeded with row offsets ----------
__global__ __launch_bounds__(NT) void scan_final_k(
    int* __restrict__ cnt_c, int* __restrict__ cnt_t, int n,
    const int* __restrict__ bsum, int nb_c,
    int* __restrict__ rp_c, int* __restrict__ rp_t) {
  int isT = blockIdx.x >= nb_c;
  int* cnt = isT ? cnt_t : cnt_c;
  int* rp = isT ? rp_t : rp_c;
  int b = isT ? blockIdx.x - nb_c : blockIdx.x;
  int offset = bsum[blockIdx.x];
  int base = b * SCAN_ELEMS + threadIdx.x * 4;

  int4 v = make_int4(0, 0, 0, 0);
  if (base + 3 < n) v = *(const int4*)&cnt[base];
  else { if (base + 0 < n) v.x = cnt[base + 0];
         if (base + 1 < n) v.y = cnt[base + 1];
         if (base + 2 < n) v.z = cnt[base + 2];
         if (base + 3 < n) v.w = cnt[base + 3]; }
  int tsum = v.x + v.y + v.z + v.w;

  __shared__ int ls[NT];
  int t = threadIdx.x;
  ls[t] = tsum;
  __syncthreads();
  for (int off = 1; off < NT; off <<= 1) {
    int u = (t >= off) ? ls[t - off] : 0;
    __syncthreads();
    ls[t] += u;
    __syncthreads();
  }
  int excl = offset + ls[t] - tsum;

  int4 o;
  o.x = excl;
  o.y = o.x + v.x;
  o.z = o.y + v.y;
  o.w = o.z + v.z;
  if (base + 3 < n) {
    *(int4*)&rp[base] = o;
    *(int4*)&cnt[base] = o;     // cursor = absolute row start (fill2 needs no rp read)
  } else {
    if (base + 0 < n) { rp[base + 0] = o.x; cnt[base + 0] = o.x; }
    if (base + 1 < n) { rp[base + 1] = o.y; cnt[base + 1] = o.y; }
    if (base + 2 < n) { rp[base + 2] = o.z; cnt[base + 2] = o.z; }
    if (base + 3 < n) { rp[base + 3] = o.w; cnt[base + 3] = o.w; }
  }
}

// ---------- fill CSR; cursor holds absolute position (one fewer random access) ----------
__global__ void fill2_k(const int* __restrict__ e_src, const int* __restrict__ e_dst, int E,
                        const int* __restrict__ c_src, const int* __restrict__ c_dst, int EC,
                        int* __restrict__ cur_c, int* __restrict__ csr_c,
                        int* __restrict__ cur_t, int* __restrict__ csr_t) {
  int i = blockIdx.x * NT + threadIdx.x;
  if (i < E) {
    int d = e_dst[i];
    csr_c[atomicAdd(&cur_c[d], 1)] = e_src[i];
  } else if (i < E + EC) {
    int j = i - E;
    int d = c_dst[j];
    csr_t[atomicAdd(&cur_t[d], 1)] = c_src[j];
  }
}

// ---------- dinv ----------
__global__ void dinv_k(const int* __restrict__ rp_c, float* __restrict__ dc,
                       const int* __restrict__ rp_t, float* __restrict__ dt, int n) {
  int i = blockIdx.x * NT + threadIdx.x;
  if (i < n) {
    dc[i] = rsqrtf((float)(rp_c[i + 1] - rp_c[i] + 1));
    dt[i] = rsqrtf((float)(rp_t[i + 1] - rp_t[i] + 1));
  }
}

// ---------- W fp32 [l][k][c] -> bf16 transposed wT[l][c][k] ----------
__global__ void convw_k(const float* __restrict__ Wc, const float* __restrict__ Wt,
                        ushort* __restrict__ wT) {
  int gid = blockIdx.x * NT + threadIdx.x;
  int l = gid >> 14, rem = gid & 16383;
  int c = rem >> 7, k = rem & 127;
  const float* W = (l < 4) ? (Wc + (size_t)l * 16384) : (Wt + (size_t)(l - 4) * 16384);
  wT[gid] = f2bf(W[k * DFEAT + c]);
}

// ---------- weighted gather, chunk-of-8 unconditional issue ----------
// Clamped neighbor index for lanes beyond degree (dup row, weight 0) -> all 8 loads
// in a chunk issue independently; serial per-neighbor chains eliminated.
template<int F32>
__device__ inline void gather8(const void* __restrict__ xv, const int* __restrict__ rp,
                               const int* __restrict__ cs, const float* __restrict__ dinv,
                               int node, int lane, int c4,
                               float& a0, float& a1, float& a2, float& a3) {
  int s0 = rp[node], deg = rp[node + 1] - s0;
  for (int p = 0; p < deg; p += 32) {
    int rem = deg - p;                    // > 0
    int mm = min(32, rem);
    int idx = min(lane, rem - 1);
    int sv = cs[s0 + p + idx];            // clamped: always a valid source
    float wv = dinv[sv];
    if (lane >= mm) wv = 0.f;             // dup lanes contribute nothing
    for (int k = 0; k < mm; k += 8) {
      int s[8]; float w[8];
#pragma unroll
      for (int j = 0; j < 8; j++) {
        s[j] = __shfl(sv, k + j, 32);
        w[j] = __shfl(wv, k + j, 32);
      }
      if (F32) {
        const float* x = (const float*)xv;
        float4 v[8];
#pragma unroll
        for (int j = 0; j < 8; j++) v[j] = *(const float4*)&x[(size_t)s[j] * DFEAT + c4];
#pragma unroll
        for (int j = 0; j < 8; j++) {
          a0 = fmaf(w[j], v[j].x, a0); a1 = fmaf(w[j], v[j].y, a1);
          a2 = fmaf(w[j], v[j].z, a2); a3 = fmaf(w[j], v[j].w, a3);
        }
      } else {
        const ushort* x = (const ushort*)xv;
        uint2 v[8];
#pragma unroll
        for (int j = 0; j < 8; j++) v[j] = *(const uint2*)&x[(size_t)s[j] * DFEAT + c4];
#pragma unroll
        for (int j = 0; j < 8; j++) accw_bf4(v[j], w[j], a0, a1, a2, a3);
      }
    }
  }
}

// ---------- aggregate-first: both graphs gather from SAME x, per-src dinv weight ----------
template<int F32>
__global__ __launch_bounds__(256) void aggregate3_k(
    const void* __restrict__ xv,
    const int* __restrict__ rpc, const int* __restrict__ csc,
    const int* __restrict__ rpt, const int* __restrict__ cst,
    const float* __restrict__ dc_, const float* __restrict__ dt_,
    ushort* __restrict__ aggc, ushort* __restrict__ aggt, int n) {
  int node = blockIdx.x * 8 + (threadIdx.x >> 5);
  if (node >= n) return;
  int lane = threadIdx.x & 31;
  int c4 = lane << 2;

  float dc = dc_[node], dt = dt_[node];
  float x0, x1, x2, x3;
  if (F32) {
    float4 v = *(const float4*)&((const float*)xv)[(size_t)node * DFEAT + c4];
    x0 = v.x; x1 = v.y; x2 = v.z; x3 = v.w;
  } else {
    uint2 sv = *(const uint2*)&((const ushort*)xv)[(size_t)node * DFEAT + c4];
    x0 = __uint_as_float(sv.x << 16);
    x1 = __uint_as_float(sv.x & 0xffff0000u);
    x2 = __uint_as_float(sv.y << 16);
    x3 = __uint_as_float(sv.y & 0xffff0000u);
  }

  float a0 = dc * x0, a1 = dc * x1, a2 = dc * x2, a3 = dc * x3;
  float b0 = dt * x0, b1 = dt * x1, b2 = dt * x2, b3 = dt * x3;

  gather8<F32>(xv, rpc, csc, dc_, node, lane, c4, a0, a1, a2, a3);
  gather8<F32>(xv, rpt, cst, dt_, node, lane, c4, b0, b1, b2, b3);

  ushort4 ha, hb;
  ha.x = f2bf(dc * a0); ha.y = f2bf(dc * a1); ha.z = f2bf(dc * a2); ha.w = f2bf(dc * a3);
  hb.x = f2bf(dt * b0); hb.y = f2bf(dt * b1); hb.z = f2bf(dt * b2); hb.w = f2bf(dt * b3);
  *(ushort4*)&aggc[(size_t)node * DFEAT + c4] = ha;
  *(ushort4*)&aggt[(size_t)node * DFEAT + c4] = hb;
}

// ---------- fused K=256 GEMM: out = agg_c@Wc + agg_t@Wt + (bc+bt) [, relu] ----------
// Operand-swapped mfma -> packed ushort4/float4 row-major stores.
// All 16 A-fragments prefetched into registers before the MFMA loop (no branches).
__global__ __launch_bounds__(256, 2) void gemmf_k(
    const ushort* __restrict__ ac, const ushort* __restrict__ at,
    const ushort* __restrict__ wTc, const ushort* __restrict__ wTt,
    const float* __restrict__ bc, const float* __restrict__ bt,
    float* __restrict__ outf, ushort* __restrict__ outh, int n, int last) {
  __shared__ __align__(16) ushort Bs[2][DFEAT * BPAD];
  __shared__ float bias[DFEAT];
  int tid = threadIdx.x;

#pragma unroll
  for (int it = 0; it < 8; it++) {
    int idx = tid + it * NT;          // 0..2047: 128 rows x 16 uint4
    int c = idx >> 4, i = idx & 15;
    *(uint4*)&Bs[0][c * BPAD + i * 8] = *(const uint4*)&wTc[c * DFEAT + i * 8];
    *(uint4*)&Bs[1][c * BPAD + i * 8] = *(const uint4*)&wTt[c * DFEAT + i * 8];
  }
  if (tid < DFEAT) bias[tid] = bc[tid] + bt[tid];
  __syncthreads();

  int wave = tid >> 6;
  int lane = tid & 63;
  int m = lane & 15;
  int q = lane >> 4;
  int row0 = blockIdx.x * GEMM_ROWS + wave * 32;
  int rA = min(row0 + m, n - 1);
  int rB = min(row0 + 16 + m, n - 1);

  uint4 fA[8], fB[8];
#pragma unroll
  for (int ks = 0; ks < 8; ks++) {                 // K=256: 0..3 conv-half, 4..7 ctrl-half
    const ushort* A = (ks < 4) ? ac : at;
    int ko = (ks & 3) * 32 + q * 8;
    fA[ks] = *(const uint4*)&A[(size_t)rA * DFEAT + ko];
    fB[ks] = *(const uint4*)&A[(size_t)rB * DFEAT + ko];
  }

  f32x4 zero4 = {0.f, 0.f, 0.f, 0.f};
  f32x4 acc0[8], acc1[8];
#pragma unroll
  for (int i = 0; i < 8; i++) { acc0[i] = zero4; acc1[i] = zero4; }

#pragma unroll
  for (int ks = 0; ks < 8; ks++) {
    int ko = (ks & 3) * 32 + q * 8;
    union { uint4 u; s8v s; } uA, uB; uA.u = fA[ks]; uB.u = fB[ks];
#pragma unroll
    for (int c8 = 0; c8 < 8; c8++) {
      s8v bf = *(const s8v*)&Bs[ks >> 2][(c8 * 16 + m) * BPAD + ko];
      acc0[c8] = __builtin_amdgcn_mfma_f32_16x16x32_bf16(bf, uA.s, acc0[c8], 0, 0, 0);
      acc1[c8] = __builtin_amdgcn_mfma_f32_16x16x32_bf16(bf, uB.s, acc1[c8], 0, 0, 0);
    }
  }

#pragma unroll
  for (int sub = 0; sub < 2; sub++) {
    int orow = row0 + sub * 16 + m;
    if (orow < n) {
#pragma unroll
      for (int c8 = 0; c8 < 8; c8++) {
        f32x4 a = sub ? acc1[c8] : acc0[c8];
        int col = c8 * 16 + q * 4;
        float4 bv = *(const float4*)&bias[col];
        float o0 = a[0] + bv.x, o1 = a[1] + bv.y, o2 = a[2] + bv.z, o3 = a[3] + bv.w;
        if (last) {
          *(float4*)&outf[(size_t)orow * DFEAT + col] = make_float4(o0, o1, o2, o3);
        } else {
          ushort4 h;
          h.x = f2bf(fmaxf(o0, 0.f));
          h.y = f2bf(fmaxf(o1, 0.f));
          h.z = f2bf(fmaxf(o2, 0.f));
          h.w = f2bf(fmaxf(o3, 0.f));
          *(ushort4*)&outh[(size_t)orow * DFEAT + col] = h;
        }
      }
    }
  }
}

extern "C" void kernel_launch(void* const* d_in, const int* in_sizes, int n_in,
                              void* d_out, int out_size, void* d_ws, size_t ws_size,
                              hipStream_t stream) {
  const float* x0 = (const float*)d_in[0];
  const int*   ei = (const int*)d_in[1];
  const int*   ci = (const int*)d_in[2];
  const float* Wc = (const float*)d_in[3];
  const float* bc = (const float*)d_in[4];
  const float* Wt = (const float*)d_in[5];
  const float* bt = (const float*)d_in[6];
  float* out = (float*)d_out;

  int n  = in_sizes[0] / DFEAT;     // 100000
  int E  = in_sizes[1] / 2;         // 600000
  int EC = in_sizes[2] / 2;         // 200000

  const int* e_src = ei;
  const int* e_dst = ei + E;
  const int* c_src = ci;
  const int* c_dst = ci + EC;

  char* p = (char*)d_ws;
  ushort* agg_c = (ushort*)p; p += (size_t)n * DFEAT * 2;
  ushort* agg_t = (ushort*)p; p += (size_t)n * DFEAT * 2;
  ushort* xh  = (ushort*)p; p += (size_t)n * DFEAT * 2;
  ushort* wT  = (ushort*)p; p += (size_t)8 * DFEAT * DFEAT * 2;
  float* dinv_c = (float*)p; p += (size_t)n * 4;
  float* dinv_t = (float*)p; p += (size_t)n * 4;
  int* cnt_c = (int*)p; p += (size_t)n * 4;
  int* cnt_t = (int*)p; p += (size_t)n * 4;
  int* rp_c  = (int*)p; p += (size_t)(n + 1) * 4;
  int* rp_t  = (int*)p; p += (size_t)(n + 1) * 4;
  int* csr_c = (int*)p; p += (size_t)E * 4;
  int* csr_t = (int*)p; p += (size_t)EC * 4;
  int* bsum  = (int*)p;

  int nb_n    = (n + NT - 1) / NT;
  int nb_node = (n + 7) / 8;
  int nb_gemm = (n + GEMM_ROWS - 1) / GEMM_ROWS;
  int nb_scan = (n + SCAN_ELEMS - 1) / SCAN_ELEMS;

  // ---- build CSR + dinv once per launch ----
  zero_k<<<(2 * n + NT - 1) / NT, NT, 0, stream>>>(cnt_c, 2 * n);
  hist2_k<<<(E + EC + NT - 1) / NT, NT, 0, stream>>>(e_dst, E, c_dst, EC, cnt_c, cnt_t);
  scan_partial_k<<<2 * nb_scan, NT, 0, stream>>>(cnt_c, cnt_t, n, bsum, nb_scan);
  scan_offsets_k<<<2, NT, 0, stream>>>(bsum, nb_scan, nb_scan, rp_c, rp_t, n);
  scan_final_k<<<2 * nb_scan, NT, 0, stream>>>(cnt_c, cnt_t, n, bsum, nb_scan, rp_c, rp_t);
  fill2_k<<<(E + EC + NT - 1) / NT, NT, 0, stream>>>(e_src, e_dst, E, c_src, c_dst, EC,
                                                     cnt_c, csr_c, cnt_t, csr_t);
  dinv_k<<<nb_n, NT, 0, stream>>>(rp_c, dinv_c, rp_t, dinv_t, n);

  // ---- weights to bf16 (x stays fp32 for layer 0; convx eliminated) ----
  convw_k<<<(8 * DFEAT * DFEAT) / NT, NT, 0, stream>>>(Wc, Wt, wT);

  // ---- layers: aggregate-first (shared-x gather), then single fused K=256 GEMM ----
  for (int i = 0; i < 4; i++) {
    if (i == 0)
      aggregate3_k<1><<<nb_node, NT, 0, stream>>>(x0, rp_c, csr_c, rp_t, csr_t,
                                                  dinv_c, dinv_t, agg_c, agg_t, n);
    else
      aggregate3_k<0><<<nb_node, NT, 0, stream>>>(xh, rp_c, csr_c, rp_t, csr_t,
                                                  dinv_c, dinv_t, agg_c, agg_t, n);
    gemmf_k<<<nb_gemm, NT, 0, stream>>>(agg_c, agg_t,
                                        wT + (size_t)i * DFEAT * DFEAT,
                                        wT + (size_t)(4 + i) * DFEAT * DFEAT,
                                        bc + i * DFEAT, bt + i * DFEAT,
                                        out, xh, n, (i == 3) ? 1 : 0);
  }
}

// Round 3
// 454.877 us; speedup vs baseline: 1.1049x; 1.1049x over previous
//
#include <hip/hip_runtime.h>
#include <cstdint>
#include <cstddef>

#define NT 256
#define DFEAT 128
#define SCAN_ELEMS 1024
#define GEMM_ROWS 128    // rows per gemm block (4 waves x 32 rows)
#define BPAD 136         // padded LDS k-stride (ushorts) for W^T tiles
#define CTRL_FLAG 0x40000000
#define SRC_MASK  0x3fffffff

typedef __attribute__((ext_vector_type(8))) short s8v;
typedef __attribute__((ext_vector_type(4))) float f32x4;

__device__ inline ushort f2bf(float f) {           // RNE fp32 -> bf16
  uint32_t u = __float_as_uint(f);
  u += 0x7fffu + ((u >> 16) & 1u);
  return (ushort)(u >> 16);
}

// ---------- zero int array ----------
__global__ void zero_k(int* __restrict__ p, int n) {
  int i = blockIdx.x * NT + threadIdx.x;
  if (i < n) p[i] = 0;
}

// ---------- histogram of dst, both graphs in one dispatch ----------
__global__ void hist2_k(const int* __restrict__ e_dst, int E,
                        const int* __restrict__ c_dst, int EC,
                        int* __restrict__ cnt_c, int* __restrict__ cnt_t) {
  int i = blockIdx.x * NT + threadIdx.x;
  if (i < E) atomicAdd(&cnt_c[e_dst[i]], 1);
  else if (i < E + EC) atomicAdd(&cnt_t[c_dst[i - E]], 1);
}

// ---------- dinv from histogram counts (before cnt is clobbered by scan) ----------
__global__ void dinv_k(const int* __restrict__ cntc, float* __restrict__ dc,
                       const int* __restrict__ cntt, float* __restrict__ dt, int n) {
  int i = blockIdx.x * NT + threadIdx.x;
  if (i < n) {
    dc[i] = rsqrtf((float)(cntc[i] + 1));
    dt[i] = rsqrtf((float)(cntt[i] + 1));
  }
}

// ---------- merged scan pass A: per-block sums of (cnt_c + cnt_t) ----------
__global__ __launch_bounds__(NT) void scan_partial_m(
    const int* __restrict__ cnt_c, const int* __restrict__ cnt_t, int n,
    int* __restrict__ bsum) {
  int base = blockIdx.x * SCAN_ELEMS + threadIdx.x * 4;
  int s = 0;
  if (base + 3 < n) {
    int4 a = *(const int4*)&cnt_c[base];
    int4 b = *(const int4*)&cnt_t[base];
    s = a.x + a.y + a.z + a.w + b.x + b.y + b.z + b.w;
  } else {
    for (int j = 0; j < 4; j++) if (base + j < n) s += cnt_c[base + j] + cnt_t[base + j];
  }
  for (int off = 32; off > 0; off >>= 1) s += __shfl_down(s, off, 64);
  __shared__ int ws[4];
  int lane = threadIdx.x & 63, w = threadIdx.x >> 6;
  if (lane == 0) ws[w] = s;
  __syncthreads();
  if (threadIdx.x == 0) bsum[blockIdx.x] = ws[0] + ws[1] + ws[2] + ws[3];
}

// ---------- merged scan pass B: exclusive prefix over block sums ----------
__global__ __launch_bounds__(NT) void scan_offsets_m(
    int* __restrict__ bsum, int nb, int* __restrict__ rp, int n) {
  __shared__ int ls[NT];
  int t = threadIdx.x;
  int v = (t < nb) ? bsum[t] : 0;
  ls[t] = v;
  __syncthreads();
  for (int off = 1; off < NT; off <<= 1) {
    int u = (t >= off) ? ls[t - off] : 0;
    __syncthreads();
    ls[t] += u;
    __syncthreads();
  }
  if (t < nb) bsum[t] = ls[t] - v;
  if (t == nb - 1) rp[n] = ls[t];
}

// ---------- merged scan pass C: rowptr + cursor (cnt_c becomes fill cursor) ----------
__global__ __launch_bounds__(NT) void scan_final_m(
    int* __restrict__ cnt_c, const int* __restrict__ cnt_t, int n,
    const int* __restrict__ bsum, int* __restrict__ rp) {
  int offset = bsum[blockIdx.x];
  int base = blockIdx.x * SCAN_ELEMS + threadIdx.x * 4;

  int4 v = make_int4(0, 0, 0, 0);
  if (base + 3 < n) {
    int4 a = *(const int4*)&cnt_c[base];
    int4 b = *(const int4*)&cnt_t[base];
    v = make_int4(a.x + b.x, a.y + b.y, a.z + b.z, a.w + b.w);
  } else {
    if (base + 0 < n) v.x = cnt_c[base + 0] + cnt_t[base + 0];
    if (base + 1 < n) v.y = cnt_c[base + 1] + cnt_t[base + 1];
    if (base + 2 < n) v.z = cnt_c[base + 2] + cnt_t[base + 2];
    if (base + 3 < n) v.w = cnt_c[base + 3] + cnt_t[base + 3];
  }
  int tsum = v.x + v.y + v.z + v.w;

  __shared__ int ls[NT];
  int t = threadIdx.x;
  ls[t] = tsum;
  __syncthreads();
  for (int off = 1; off < NT; off <<= 1) {
    int u = (t >= off) ? ls[t - off] : 0;
    __syncthreads();
    ls[t] += u;
    __syncthreads();
  }
  int excl = offset + ls[t] - tsum;

  int4 o;
  o.x = excl;
  o.y = o.x + v.x;
  o.z = o.y + v.y;
  o.w = o.z + v.z;
  if (base + 3 < n) {
    *(int4*)&rp[base] = o;
    *(int4*)&cnt_c[base] = o;   // cursor = absolute row start
  } else {
    if (base + 0 < n) { rp[base + 0] = o.x; cnt_c[base + 0] = o.x; }
    if (base + 1 < n) { rp[base + 1] = o.y; cnt_c[base + 1] = o.y; }
    if (base + 2 < n) { rp[base + 2] = o.z; cnt_c[base + 2] = o.z; }
    if (base + 3 < n) { rp[base + 3] = o.w; cnt_c[base + 3] = o.w; }
  }
}

// ---------- fill merged CSR, 4 edges/thread (independent atomic chains) ----------
__global__ void fill4_k(const int* __restrict__ e_src, const int* __restrict__ e_dst, int E,
                        const int* __restrict__ c_src, const int* __restrict__ c_dst, int EC,
                        int* __restrict__ cur, int* __restrict__ csr) {
  int E4 = E >> 2, EC4 = EC >> 2;
  int i = blockIdx.x * NT + threadIdx.x;
  if (i < E4) {
    int4 s = ((const int4*)e_src)[i];
    int4 d = ((const int4*)e_dst)[i];
    csr[atomicAdd(&cur[d.x], 1)] = s.x;
    csr[atomicAdd(&cur[d.y], 1)] = s.y;
    csr[atomicAdd(&cur[d.z], 1)] = s.z;
    csr[atomicAdd(&cur[d.w], 1)] = s.w;
  } else if (i < E4 + EC4) {
    int j = i - E4;
    int4 s = ((const int4*)c_src)[j];
    int4 d = ((const int4*)c_dst)[j];
    csr[atomicAdd(&cur[d.x], 1)] = s.x | CTRL_FLAG;
    csr[atomicAdd(&cur[d.y], 1)] = s.y | CTRL_FLAG;
    csr[atomicAdd(&cur[d.z], 1)] = s.z | CTRL_FLAG;
    csr[atomicAdd(&cur[d.w], 1)] = s.w | CTRL_FLAG;
  } else {
    int j = i - E4 - EC4;
    int et = E & 3, ct = EC & 3;
    if (j < et) {
      int idx = 4 * E4 + j;
      csr[atomicAdd(&cur[e_dst[idx]], 1)] = e_src[idx];
    } else if (j - et < ct) {
      int idx = 4 * EC4 + (j - et);
      csr[atomicAdd(&cur[c_dst[idx]], 1)] = c_src[idx] | CTRL_FLAG;
    }
  }
}

// ---------- x fp32 -> bf16 ----------
__global__ void convx_k(const float* __restrict__ x, ushort* __restrict__ xh, int total4) {
  int i = blockIdx.x * NT + threadIdx.x;
  if (i < total4) {
    float4 v = ((const float4*)x)[i];
    ushort4 o;
    o.x = f2bf(v.x); o.y = f2bf(v.y); o.z = f2bf(v.z); o.w = f2bf(v.w);
    ((ushort4*)xh)[i] = o;
  }
}

// ---------- W fp32 [l][k][c] -> bf16 transposed wT[l][c][k] ----------
__global__ void convw_k(const float* __restrict__ Wc, const float* __restrict__ Wt,
                        ushort* __restrict__ wT) {
  int gid = blockIdx.x * NT + threadIdx.x;
  int l = gid >> 14, rem = gid & 16383;
  int c = rem >> 7, k = rem & 127;
  const float* W = (l < 4) ? (Wc + (size_t)l * 16384) : (Wt + (size_t)(l - 4) * 16384);
  wT[gid] = f2bf(W[k * DFEAT + c]);
}

// ---------- merged-graph aggregate: ONE CSR walk feeds both (a,b) accumulators ----------
// agg_c[v] = bf16( dc[v]*( dc[v]*x[v] + sum_{conv edges} dc[s]*x[s] ) ), same for ctrl.
// Chunk-of-8 unconditional issue; flagged srcs route weight to wa or wb (other = 0).
__global__ __launch_bounds__(256) void aggregate4_k(
    const ushort* __restrict__ xh,
    const int* __restrict__ rp, const int* __restrict__ cs,
    const float* __restrict__ dc_, const float* __restrict__ dt_,
    ushort* __restrict__ aggc, ushort* __restrict__ aggt, int n) {
  int node = blockIdx.x * 8 + (threadIdx.x >> 5);
  if (node >= n) return;
  int lane = threadIdx.x & 31;
  int c4 = lane << 2;

  float dc = dc_[node], dt = dt_[node];
  uint2 sv0 = *(const uint2*)&xh[(size_t)node * DFEAT + c4];
  float x0 = __uint_as_float(sv0.x << 16);
  float x1 = __uint_as_float(sv0.x & 0xffff0000u);
  float x2 = __uint_as_float(sv0.y << 16);
  float x3 = __uint_as_float(sv0.y & 0xffff0000u);

  float a0 = dc * x0, a1 = dc * x1, a2 = dc * x2, a3 = dc * x3;
  float b0 = dt * x0, b1 = dt * x1, b2 = dt * x2, b3 = dt * x3;

  int s0 = rp[node], deg = rp[node + 1] - s0;
  for (int p = 0; p < deg; p += 32) {
    int rem = deg - p;                    // > 0
    int mm = min(32, rem);
    int idx = min(lane, rem - 1);
    int v = cs[s0 + p + idx];             // clamped: always valid
    int sidx = v & SRC_MASK;
    int isT = (v >> 30) & 1;
    float w = isT ? dt_[sidx] : dc_[sidx];
    float wa = (lane < mm && !isT) ? w : 0.f;
    float wb = (lane < mm && isT) ? w : 0.f;
    for (int k = 0; k < mm; k += 8) {
      int s[8]; float wA[8], wB[8];
#pragma unroll
      for (int j = 0; j < 8; j++) {
        s[j] = __shfl(sidx, k + j, 32);
        wA[j] = __shfl(wa, k + j, 32);
        wB[j] = __shfl(wb, k + j, 32);
      }
      uint2 r[8];
#pragma unroll
      for (int j = 0; j < 8; j++) r[j] = *(const uint2*)&xh[(size_t)s[j] * DFEAT + c4];
#pragma unroll
      for (int j = 0; j < 8; j++) {
        float e0 = __uint_as_float(r[j].x << 16);
        float e1 = __uint_as_float(r[j].x & 0xffff0000u);
        float e2 = __uint_as_float(r[j].y << 16);
        float e3 = __uint_as_float(r[j].y & 0xffff0000u);
        a0 = fmaf(wA[j], e0, a0); a1 = fmaf(wA[j], e1, a1);
        a2 = fmaf(wA[j], e2, a2); a3 = fmaf(wA[j], e3, a3);
        b0 = fmaf(wB[j], e0, b0); b1 = fmaf(wB[j], e1, b1);
        b2 = fmaf(wB[j], e2, b2); b3 = fmaf(wB[j], e3, b3);
      }
    }
  }

  ushort4 ha, hb;
  ha.x = f2bf(dc * a0); ha.y = f2bf(dc * a1); ha.z = f2bf(dc * a2); ha.w = f2bf(dc * a3);
  hb.x = f2bf(dt * b0); hb.y = f2bf(dt * b1); hb.z = f2bf(dt * b2); hb.w = f2bf(dt * b3);
  *(ushort4*)&aggc[(size_t)node * DFEAT + c4] = ha;
  *(ushort4*)&aggt[(size_t)node * DFEAT + c4] = hb;
}

// ---------- fused K=256 GEMM: out = agg_c@Wc + agg_t@Wt + (bc+bt) [, relu] ----------
// Operand-swapped mfma -> packed ushort4/float4 row-major stores.
// All 16 A-fragments prefetched into registers before the MFMA loop (no branches).
__global__ __launch_bounds__(256, 2) void gemmf_k(
    const ushort* __restrict__ ac, const ushort* __restrict__ at,
    const ushort* __restrict__ wTc, const ushort* __restrict__ wTt,
    const float* __restrict__ bc, const float* __restrict__ bt,
    float* __restrict__ outf, ushort* __restrict__ outh, int n, int last) {
  __shared__ __align__(16) ushort Bs[2][DFEAT * BPAD];
  __shared__ float bias[DFEAT];
  int tid = threadIdx.x;

#pragma unroll
  for (int it = 0; it < 8; it++) {
    int idx = tid + it * NT;          // 0..2047: 128 rows x 16 uint4
    int c = idx >> 4, i = idx & 15;
    *(uint4*)&Bs[0][c * BPAD + i * 8] = *(const uint4*)&wTc[c * DFEAT + i * 8];
    *(uint4*)&Bs[1][c * BPAD + i * 8] = *(const uint4*)&wTt[c * DFEAT + i * 8];
  }
  if (tid < DFEAT) bias[tid] = bc[tid] + bt[tid];
  __syncthreads();

  int wave = tid >> 6;
  int lane = tid & 63;
  int m = lane & 15;
  int q = lane >> 4;
  int row0 = blockIdx.x * GEMM_ROWS + wave * 32;
  int rA = min(row0 + m, n - 1);
  int rB = min(row0 + 16 + m, n - 1);

  uint4 fA[8], fB[8];
#pragma unroll
  for (int ks = 0; ks < 8; ks++) {                 // K=256: 0..3 conv-half, 4..7 ctrl-half
    const ushort* A = (ks < 4) ? ac : at;
    int ko = (ks & 3) * 32 + q * 8;
    fA[ks] = *(const uint4*)&A[(size_t)rA * DFEAT + ko];
    fB[ks] = *(const uint4*)&A[(size_t)rB * DFEAT + ko];
  }

  f32x4 zero4 = {0.f, 0.f, 0.f, 0.f};
  f32x4 acc0[8], acc1[8];
#pragma unroll
  for (int i = 0; i < 8; i++) { acc0[i] = zero4; acc1[i] = zero4; }

#pragma unroll
  for (int ks = 0; ks < 8; ks++) {
    int ko = (ks & 3) * 32 + q * 8;
    union { uint4 u; s8v s; } uA, uB; uA.u = fA[ks]; uB.u = fB[ks];
#pragma unroll
    for (int c8 = 0; c8 < 8; c8++) {
      s8v bf = *(const s8v*)&Bs[ks >> 2][(c8 * 16 + m) * BPAD + ko];
      acc0[c8] = __builtin_amdgcn_mfma_f32_16x16x32_bf16(bf, uA.s, acc0[c8], 0, 0, 0);
      acc1[c8] = __builtin_amdgcn_mfma_f32_16x16x32_bf16(bf, uB.s, acc1[c8], 0, 0, 0);
    }
  }

#pragma unroll
  for (int sub = 0; sub < 2; sub++) {
    int orow = row0 + sub * 16 + m;
    if (orow < n) {
#pragma unroll
      for (int c8 = 0; c8 < 8; c8++) {
        f32x4 a = sub ? acc1[c8] : acc0[c8];
        int col = c8 * 16 + q * 4;
        float4 bv = *(const float4*)&bias[col];
        float o0 = a[0] + bv.x, o1 = a[1] + bv.y, o2 = a[2] + bv.z, o3 = a[3] + bv.w;
        if (last) {
          *(float4*)&outf[(size_t)orow * DFEAT + col] = make_float4(o0, o1, o2, o3);
        } else {
          ushort4 h;
          h.x = f2bf(fmaxf(o0, 0.f));
          h.y = f2bf(fmaxf(o1, 0.f));
          h.z = f2bf(fmaxf(o2, 0.f));
          h.w = f2bf(fmaxf(o3, 0.f));
          *(ushort4*)&outh[(size_t)orow * DFEAT + col] = h;
        }
      }
    }
  }
}

extern "C" void kernel_launch(void* const* d_in, const int* in_sizes, int n_in,
                              void* d_out, int out_size, void* d_ws, size_t ws_size,
                              hipStream_t stream) {
  const float* x0 = (const float*)d_in[0];
  const int*   ei = (const int*)d_in[1];
  const int*   ci = (const int*)d_in[2];
  const float* Wc = (const float*)d_in[3];
  const float* bc = (const float*)d_in[4];
  const float* Wt = (const float*)d_in[5];
  const float* bt = (const float*)d_in[6];
  float* out = (float*)d_out;

  int n  = in_sizes[0] / DFEAT;     // 100000
  int E  = in_sizes[1] / 2;         // 600000
  int EC = in_sizes[2] / 2;         // 200000

  const int* e_src = ei;
  const int* e_dst = ei + E;
  const int* c_src = ci;
  const int* c_dst = ci + EC;

  char* p = (char*)d_ws;
  ushort* agg_c = (ushort*)p; p += (size_t)n * DFEAT * 2;
  ushort* agg_t = (ushort*)p; p += (size_t)n * DFEAT * 2;
  ushort* xh  = (ushort*)p; p += (size_t)n * DFEAT * 2;
  ushort* wT  = (ushort*)p; p += (size_t)8 * DFEAT * DFEAT * 2;
  float* dinv_c = (float*)p; p += (size_t)n * 4;
  float* dinv_t = (float*)p; p += (size_t)n * 4;
  int* cnt_c = (int*)p; p += (size_t)n * 4;     // histogram -> cursor
  int* cnt_t = (int*)p; p += (size_t)n * 4;     // histogram
  int* rp    = (int*)p; p += (size_t)(n + 1) * 4;
  int* csr   = (int*)p; p += (size_t)(E + EC) * 4;
  int* bsum  = (int*)p;

  int nb_n    = (n + NT - 1) / NT;
  int nb_node = (n + 7) / 8;
  int nb_gemm = (n + GEMM_ROWS - 1) / GEMM_ROWS;
  int nb_scan = (n + SCAN_ELEMS - 1) / SCAN_ELEMS;
  int nb_fill = ((E >> 2) + (EC >> 2) + 8 + NT - 1) / NT;

  // ---- build merged CSR + dinv once per launch ----
  zero_k<<<(2 * n + NT - 1) / NT, NT, 0, stream>>>(cnt_c, 2 * n);
  hist2_k<<<(E + EC + NT - 1) / NT, NT, 0, stream>>>(e_dst, E, c_dst, EC, cnt_c, cnt_t);
  dinv_k<<<nb_n, NT, 0, stream>>>(cnt_c, dinv_c, cnt_t, dinv_t, n);
  scan_partial_m<<<nb_scan, NT, 0, stream>>>(cnt_c, cnt_t, n, bsum);
  scan_offsets_m<<<1, NT, 0, stream>>>(bsum, nb_scan, rp, n);
  scan_final_m<<<nb_scan, NT, 0, stream>>>(cnt_c, cnt_t, n, bsum, rp);
  fill4_k<<<nb_fill, NT, 0, stream>>>(e_src, e_dst, E, c_src, c_dst, EC, cnt_c, csr);

  // ---- bf16 conversions (gathers must stay narrow: 256B/row) ----
  convx_k<<<(n * 32 + NT - 1) / NT, NT, 0, stream>>>(x0, xh, n * 32);
  convw_k<<<(8 * DFEAT * DFEAT) / NT, NT, 0, stream>>>(Wc, Wt, wT);

  // ---- layers: merged-CSR aggregate, then single fused K=256 GEMM ----
  for (int i = 0; i < 4; i++) {
    aggregate4_k<<<nb_node, NT, 0, stream>>>(xh, rp, csr, dinv_c, dinv_t,
                                             agg_c, agg_t, n);
    gemmf_k<<<nb_gemm, NT, 0, stream>>>(agg_c, agg_t,
                                        wT + (size_t)i * DFEAT * DFEAT,
                                        wT + (size_t)(4 + i) * DFEAT * DFEAT,
                                        bc + i * DFEAT, bt + i * DFEAT,
                                        out, xh, n, (i == 3) ? 1 : 0);
  }
}